// Round 5
// baseline (181.002 us; speedup 1.0000x reference)
//
#include <hip/hip_runtime.h>
#include <hip/hip_bf16.h>

typedef __bf16 bf16x8 __attribute__((ext_vector_type(8)));
typedef float  f32x4  __attribute__((ext_vector_type(4)));

#define NSEG   39
#define NCAT   26
#define NCTS   13
#define VOCAB  100000
#define DIM    64
#define HID    512
#define KTOT   2496   // 39*64
#define MT     64     // rows per block

__global__ void w1_to_bf16(const float* __restrict__ w1, ushort* __restrict__ w1b, int n4) {
    int i = blockIdx.x * blockDim.x + threadIdx.x;
    if (i >= n4) return;
    f32x4 v = ((const f32x4*)w1)[i];
    ushort4 o;
    o.x = __builtin_bit_cast(unsigned short, (__bf16)v[0]);
    o.y = __builtin_bit_cast(unsigned short, (__bf16)v[1]);
    o.z = __builtin_bit_cast(unsigned short, (__bf16)v[2]);
    o.w = __builtin_bit_cast(unsigned short, (__bf16)v[3]);
    ((ushort4*)w1b)[i] = o;
}

template<bool W1BF>
__global__ __launch_bounds__(768, 3)
void fused_net(const float* __restrict__ x,      // B x 39
               const float* __restrict__ emb,    // 26 x V x 64
               const float* __restrict__ ctsW,   // 13 x 64
               const float* __restrict__ ctsB,   // 13 x 64
               const void*  __restrict__ W1p,    // 512 x 2496 (bf16 or f32)
               const float* __restrict__ b1,     // 512
               const float* __restrict__ W2,     // 512
               const float* __restrict__ b2,     // 1
               float* __restrict__ out)          // B
{
    const int tid  = threadIdx.x;
    const int lane = tid & 63;
    const int wave = tid >> 6;     // 0..7 consumers, 8..11 producers
    const int m0   = blockIdx.x * MT;

    __shared__ float xs[MT * NSEG];                      // 9984 B
    __shared__ float ctsw_s[NCTS * DIM];                 // 3328 B
    __shared__ float ctsb_s[NCTS * DIM];                 // 3328 B
    __shared__ __align__(16) ushort Abuf[2][MT * DIM];   // 2 x 8 KB bf16, swizzled
    __shared__ float hsum[MT];                           // 256 B

    for (int e = tid; e < MT * NSEG; e += 768)
        xs[e] = x[(size_t)m0 * NSEG + e];
    for (int e = tid; e < NCTS * DIM; e += 768) {
        ctsw_s[e] = ctsW[e];
        ctsb_s[e] = ctsB[e];
    }
    if (tid < MT) hsum[tid] = 0.f;
    __syncthreads();

    const ushort* W1b = (const ushort*)W1p;
    const float*  W1f = (const float*)W1p;

    // ---------------- consumer state (waves 0..7) ----------------
    unsigned bbase[4];
#pragma unroll
    for (int ni = 0; ni < 4; ++ni)
        bbase[ni] = (unsigned)(wave * 64 + ni * 16 + (lane & 15)) * KTOT + ((lane >> 4) << 3);

    bf16x8 bfr[2][2][4];  // [set][ks][ni]
    auto loadB = [&](int t, int set) {
#pragma unroll
        for (int ks = 0; ks < 2; ++ks)
#pragma unroll
            for (int ni = 0; ni < 4; ++ni) {
                unsigned off = bbase[ni] + t * 64 + ks * 32;
                if constexpr (W1BF) {
                    bfr[set][ks][ni] = *(const bf16x8*)(W1b + off);
                } else {
                    f32x4 u0 = *(const f32x4*)(W1f + off);
                    f32x4 u1 = *(const f32x4*)(W1f + off + 4);
                    bf16x8 tmp;
#pragma unroll
                    for (int k = 0; k < 4; ++k) {
                        tmp[k]     = (__bf16)u0[k];
                        tmp[4 + k] = (__bf16)u1[k];
                    }
                    bfr[set][ks][ni] = tmp;
                }
            }
    };

    f32x4 acc[4][4];
#pragma unroll
    for (int mi = 0; mi < 4; ++mi)
#pragma unroll
        for (int ni = 0; ni < 4; ++ni)
            acc[mi][ni] = (f32x4){0.f, 0.f, 0.f, 0.f};

    // ---------------- producer state (waves 8..11) ----------------
    // 256 threads: row r (4 thr/row), 16-float group q4. Content chunks 2q4,2q4+1
    // (8 bf16 each) -> physical slot = chunk ^ (r&7).
    const int tp  = tid - 512;          // 0..255 when producer
    const int r   = (tp < 0 ? 0 : tp) >> 2;
    const int q4  = (tp < 0 ? 0 : tp) & 3;

    f32x4 g[4][4];                      // gather ring, depth 4

    auto issueG = [&](int seg, int slot) {
        int idx = (int)xs[r * NSEG + seg];
        const float* p = emb + ((size_t)seg * VOCAB + (size_t)idx) * DIM + q4 * 16;
        g[slot][0] = __builtin_nontemporal_load((const f32x4*)(p));
        g[slot][1] = __builtin_nontemporal_load((const f32x4*)(p + 4));
        g[slot][2] = __builtin_nontemporal_load((const f32x4*)(p + 8));
        g[slot][3] = __builtin_nontemporal_load((const f32x4*)(p + 12));
    };

    auto writeA = [&](int seg, int slot, int buf, bool norelu) {
        float v[16];
        if (seg < NCAT) {
#pragma unroll
            for (int i = 0; i < 4; ++i)
#pragma unroll
                for (int w = 0; w < 4; ++w) v[i * 4 + w] = g[slot][i][w];
            if (!norelu) {
#pragma unroll
                for (int k = 0; k < 16; ++k) v[k] = fmaxf(v[k], 0.f);
            }
        } else {
            int jj = seg - NCAT;
            float sx = xs[r * NSEG + seg];
#pragma unroll
            for (int i = 0; i < 4; ++i) {
                f32x4 w  = *(const f32x4*)&ctsw_s[jj * DIM + q4 * 16 + i * 4];
                f32x4 bb = *(const f32x4*)&ctsb_s[jj * DIM + q4 * 16 + i * 4];
#pragma unroll
                for (int k = 0; k < 4; ++k)
                    v[i * 4 + k] = fmaxf(fmaf(sx, w[k], bb[k]), 0.f);
            }
        }
        bf16x8 o0, o1;
#pragma unroll
        for (int k = 0; k < 8; ++k) { o0[k] = (__bf16)v[k]; o1[k] = (__bf16)v[8 + k]; }
        const int p0 = (2 * q4) ^ (r & 7);
        const int p1 = (2 * q4 + 1) ^ (r & 7);
        *(bf16x8*)&Abuf[buf][r * DIM + p0 * 8] = o0;
        *(bf16x8*)&Abuf[buf][r * DIM + p1 * 8] = o1;
    };

    // ---------------- prologue ----------------
    if (wave < 8) {
        loadB(0, 0);
    } else {
        issueG(0, 0); issueG(1, 1); issueG(2, 2); issueG(3, 3);
        writeA(0, 0, 0, /*norelu=*/true);
    }
    asm volatile("s_waitcnt lgkmcnt(0)" ::: "memory");
    __builtin_amdgcn_s_barrier();
    __builtin_amdgcn_sched_barrier(0);

    // ---------------- main loop: one barrier per K-step ----------------
    for (int tt = 0; tt < 40; tt += 4) {
#pragma unroll
        for (int j = 0; j < 4; ++j) {
            const int t = tt + j;
            if (t < NSEG) {
                if (wave < 8) {
                    if (t + 1 < NSEG) loadB(t + 1, (j + 1) & 1);
#pragma unroll
                    for (int ks = 0; ks < 2; ++ks) {
                        bf16x8 afr[4];
#pragma unroll
                        for (int mi = 0; mi < 4; ++mi) {
                            int R = mi * 16 + (lane & 15);
                            int C = ks * 4 + (lane >> 4);
                            afr[mi] = *(const bf16x8*)&Abuf[j & 1][R * DIM + ((C ^ (R & 7)) << 3)];
                        }
                        __builtin_amdgcn_s_setprio(1);
#pragma unroll
                        for (int ni = 0; ni < 4; ++ni)
#pragma unroll
                            for (int mi = 0; mi < 4; ++mi)
                                acc[mi][ni] = __builtin_amdgcn_mfma_f32_16x16x32_bf16(
                                    afr[mi], bfr[j & 1][ks][ni], acc[mi][ni], 0, 0, 0);
                        __builtin_amdgcn_s_setprio(0);
                    }
                } else {
                    if (t + 4 < NCAT) issueG(t + 4, j);          // slot (t+4)%4 == j
                    if (t + 1 < NSEG) writeA(t + 1, (j + 1) & 3, (j + 1) & 1, false);
                }
                asm volatile("s_waitcnt lgkmcnt(0)" ::: "memory");
                __builtin_amdgcn_s_barrier();
                __builtin_amdgcn_sched_barrier(0);
            }
        }
    }

    // ---------------- epilogue (consumers only) ----------------
    if (wave < 8) {
        float pv[4][4];
#pragma unroll
        for (int mi = 0; mi < 4; ++mi)
#pragma unroll
            for (int rg = 0; rg < 4; ++rg) pv[mi][rg] = 0.f;

#pragma unroll
        for (int ni = 0; ni < 4; ++ni) {
            int n = wave * 64 + ni * 16 + (lane & 15);
            float b1v = b1[n];
            float w2v = W2[n];
#pragma unroll
            for (int mi = 0; mi < 4; ++mi)
#pragma unroll
                for (int rg = 0; rg < 4; ++rg) {
                    float h = fmaxf(acc[mi][ni][rg] + b1v, 0.f);
                    pv[mi][rg] = fmaf(h, w2v, pv[mi][rg]);
                }
        }

#pragma unroll
        for (int m = 1; m < 16; m <<= 1)
#pragma unroll
            for (int mi = 0; mi < 4; ++mi)
#pragma unroll
                for (int rg = 0; rg < 4; ++rg)
                    pv[mi][rg] += __shfl_xor(pv[mi][rg], m, 64);

        if ((lane & 15) == 0) {
            int rq = lane >> 4;
#pragma unroll
            for (int mi = 0; mi < 4; ++mi)
#pragma unroll
                for (int rg = 0; rg < 4; ++rg)
                    atomicAdd(&hsum[mi * 16 + rq * 4 + rg], pv[mi][rg]);
        }
    }
    __syncthreads();

    if (tid < MT) out[m0 + tid] = expf(hsum[tid] + b2[0]);
}

extern "C" void kernel_launch(void* const* d_in, const int* in_sizes, int n_in,
                              void* d_out, int out_size, void* d_ws, size_t ws_size,
                              hipStream_t stream) {
    const float* x    = (const float*)d_in[0];
    const float* emb  = (const float*)d_in[1];
    const float* ctsW = (const float*)d_in[2];
    const float* ctsB = (const float*)d_in[3];
    const float* W1   = (const float*)d_in[4];
    const float* b1   = (const float*)d_in[5];
    const float* W2   = (const float*)d_in[6];
    const float* b2   = (const float*)d_in[7];
    float* out = (float*)d_out;

    const int Bn   = in_sizes[0] / NSEG;         // 16384
    const int nblk = Bn / MT;                    // 256
    const size_t w1b_bytes = (size_t)HID * KTOT * sizeof(unsigned short);

    if (ws_size >= w1b_bytes) {
        ushort* W1b = (ushort*)d_ws;
        int n4 = HID * KTOT / 4;
        w1_to_bf16<<<(n4 + 255) / 256, 256, 0, stream>>>(W1, W1b, n4);
        fused_net<true><<<nblk, 768, 0, stream>>>(x, emb, ctsW, ctsB, (const void*)W1b,
                                                  b1, W2, b2, out);
    } else {
        fused_net<false><<<nblk, 768, 0, stream>>>(x, emb, ctsW, ctsB, (const void*)W1,
                                                   b1, W2, b2, out);
    }
}

// Round 6
// 165.745 us; speedup vs baseline: 1.0921x; 1.0921x over previous
//
#include <hip/hip_runtime.h>
#include <hip/hip_bf16.h>

typedef __bf16 bf16x8 __attribute__((ext_vector_type(8)));
typedef float  f32x4  __attribute__((ext_vector_type(4)));

#define NSEG   39
#define NCAT   26
#define NCTS   13
#define VOCAB  100000
#define DIM    64
#define HID    512
#define KTOT   2496   // 39*64
#define MT     64     // rows per block / A-tile

// ---------------- kernel: W1 f32 -> bf16 ----------------
__global__ void w1_to_bf16(const float* __restrict__ w1, ushort* __restrict__ w1b, int n4) {
    int i = blockIdx.x * blockDim.x + threadIdx.x;
    if (i >= n4) return;
    f32x4 v = ((const f32x4*)w1)[i];
    ushort4 o;
    o.x = __builtin_bit_cast(unsigned short, (__bf16)v[0]);
    o.y = __builtin_bit_cast(unsigned short, (__bf16)v[1]);
    o.z = __builtin_bit_cast(unsigned short, (__bf16)v[2]);
    o.w = __builtin_bit_cast(unsigned short, (__bf16)v[3]);
    ((ushort4*)w1b)[i] = o;
}

// ---------------- kernel: build swizzled bf16 A ----------------
// A layout: per (mtile, seg): 8 KB chunk = 64 rows x 128 B; within a row,
// content chunk c (8 bf16) sits at physical slot p = c ^ (r&7).
// Thread granularity: 4 threads per (row,seg), 64 B gather read each.
__global__ __launch_bounds__(256)
void build_A(const float* __restrict__ x, const float* __restrict__ emb,
             const float* __restrict__ ctsW, const float* __restrict__ ctsB,
             ushort* __restrict__ A, int total4)
{
    int i = blockIdx.x * 256 + threadIdx.x;
    const int stride = gridDim.x * 256;
    for (; i < total4; i += stride) {
        const int c2     = i & 3;          // 16-float group
        const int rowseg = i >> 2;
        const int row    = rowseg / NSEG;  // const-div -> magic mul
        const int seg    = rowseg - row * NSEG;
        const int r      = row & 63;
        const int mtile  = row >> 6;

        float v[16];
        if (seg < NCAT) {
            int idx = (int)x[rowseg];
            const float* p = emb + ((size_t)seg * VOCAB + (size_t)idx) * DIM + c2 * 16;
            f32x4 a0 = __builtin_nontemporal_load((const f32x4*)(p));
            f32x4 a1 = __builtin_nontemporal_load((const f32x4*)(p + 4));
            f32x4 a2 = __builtin_nontemporal_load((const f32x4*)(p + 8));
            f32x4 a3 = __builtin_nontemporal_load((const f32x4*)(p + 12));
#pragma unroll
            for (int k = 0; k < 4; ++k) {
                v[k] = a0[k]; v[4 + k] = a1[k]; v[8 + k] = a2[k]; v[12 + k] = a3[k];
            }
            if (seg >= 1) {
#pragma unroll
                for (int k = 0; k < 16; ++k) v[k] = fmaxf(v[k], 0.f);
            }
        } else {
            int jj = seg - NCAT;
            float sx = x[rowseg];
            const float* wp = ctsW + jj * DIM + c2 * 16;
            const float* bp = ctsB + jj * DIM + c2 * 16;
#pragma unroll
            for (int q = 0; q < 4; ++q) {
                f32x4 w  = *(const f32x4*)(wp + q * 4);
                f32x4 bb = *(const f32x4*)(bp + q * 4);
#pragma unroll
                for (int k = 0; k < 4; ++k)
                    v[q * 4 + k] = fmaxf(fmaf(sx, w[k], bb[k]), 0.f);
            }
        }

        bf16x8 o0, o1;
#pragma unroll
        for (int k = 0; k < 8; ++k) { o0[k] = (__bf16)v[k]; o1[k] = (__bf16)v[8 + k]; }

        const size_t base = (size_t)(mtile * NSEG + seg) * 4096 + r * 64; // ushort units
        const int p0 = (2 * c2)     ^ (r & 7);
        const int p1 = (2 * c2 + 1) ^ (r & 7);
        *(bf16x8*)&A[base + p0 * 8] = o0;
        *(bf16x8*)&A[base + p1 * 8] = o1;
    }
}

// ---------------- kernel: GEMM + epilogue ----------------
template<bool W1BF>
__global__ __launch_bounds__(512, 1)
void gemm_net(const ushort* __restrict__ A,     // swizzled bf16, 256 x 39 x 8KB
              const void*  __restrict__ W1p,    // 512 x 2496 (bf16 or f32)
              const float* __restrict__ b1,     // 512
              const float* __restrict__ W2,     // 512
              const float* __restrict__ b2,     // 1
              float* __restrict__ out)          // B
{
    const int tid  = threadIdx.x;
    const int lane = tid & 63;
    const int wave = tid >> 6;
    const int m0   = blockIdx.x * MT;

    __shared__ __align__(16) ushort Abuf[3][MT * DIM];   // 3 x 8 KB, swizzled
    __shared__ float hsum[MT];
    if (tid < MT) hsum[tid] = 0.f;

    unsigned bbase[4];
#pragma unroll
    for (int ni = 0; ni < 4; ++ni)
        bbase[ni] = (unsigned)(wave * 64 + ni * 16 + (lane & 15)) * KTOT + ((lane >> 4) << 3);

    const ushort* W1b = (const ushort*)W1p;
    const float*  W1f = (const float*)W1p;

    bf16x8 bfr[2][2][4];  // [set][ks][ni]
    auto loadB = [&](int t, int set) {
#pragma unroll
        for (int ks = 0; ks < 2; ++ks)
#pragma unroll
            for (int ni = 0; ni < 4; ++ni) {
                unsigned off = bbase[ni] + t * 64 + ks * 32;
                if constexpr (W1BF) {
                    bfr[set][ks][ni] = *(const bf16x8*)(W1b + off);
                } else {
                    f32x4 u0 = *(const f32x4*)(W1f + off);
                    f32x4 u1 = *(const f32x4*)(W1f + off + 4);
                    bf16x8 tmp;
#pragma unroll
                    for (int k = 0; k < 4; ++k) {
                        tmp[k]     = (__bf16)u0[k];
                        tmp[4 + k] = (__bf16)u1[k];
                    }
                    bfr[set][ks][ni] = tmp;
                }
            }
    };

    const ushort* Atile = A + (size_t)blockIdx.x * (NSEG * 4096);

    // stage one 8 KB K-chunk: each wave DMAs 1 KB (lane-contiguous, linear LDS)
    auto stage = [&](int t, int buf) {
        const ushort* gp = Atile + t * 4096 + ((wave << 6) + lane) * 8;
        __builtin_amdgcn_global_load_lds(
            (const __attribute__((address_space(1))) unsigned int*)gp,
            (__attribute__((address_space(3))) unsigned int*)&Abuf[buf][wave << 9],
            16, 0, 0);
    };

    f32x4 acc[4][4];
#pragma unroll
    for (int mi = 0; mi < 4; ++mi)
#pragma unroll
        for (int ni = 0; ni < 4; ++ni)
            acc[mi][ni] = (f32x4){0.f, 0.f, 0.f, 0.f};

    // prologue: 2-deep A prefetch + first B set; vmcnt(9) keeps stage(1)+loadB(0) in flight
    stage(0, 0);
    stage(1, 1);
    loadB(0, 0);
    if constexpr (W1BF) asm volatile("s_waitcnt vmcnt(9)" ::: "memory");
    else                asm volatile("s_waitcnt vmcnt(17)" ::: "memory");
    __builtin_amdgcn_s_barrier();
    __builtin_amdgcn_sched_barrier(0);

    // main loop: buf period 3, B-set period 2 -> unroll by 6
    for (int tt = 0; tt < 42; tt += 6) {
#pragma unroll
        for (int j = 0; j < 6; ++j) {
            const int t = tt + j;
            if (t < NSEG) {
                if (t + 2 < NSEG) stage(t + 2, (j + 2) % 3);
                if (t + 1 < NSEG) loadB(t + 1, (j + 1) & 1);

#pragma unroll
                for (int ks = 0; ks < 2; ++ks) {
                    bf16x8 afr[4];
#pragma unroll
                    for (int mi = 0; mi < 4; ++mi) {
                        int R = mi * 16 + (lane & 15);
                        int C = ks * 4 + (lane >> 4);
                        afr[mi] = *(const bf16x8*)&Abuf[j % 3][R * DIM + ((C ^ (R & 7)) << 3)];
                    }
                    __builtin_amdgcn_s_setprio(1);
#pragma unroll
                    for (int ni = 0; ni < 4; ++ni)
#pragma unroll
                        for (int mi = 0; mi < 4; ++mi)
                            acc[mi][ni] = __builtin_amdgcn_mfma_f32_16x16x32_bf16(
                                afr[mi], bfr[j & 1][ks][ni], acc[mi][ni], 0, 0, 0);
                    __builtin_amdgcn_s_setprio(0);
                }

                // counted wait: only the oldest (next step's stage) must retire
                if constexpr (W1BF) asm volatile("s_waitcnt vmcnt(9)" ::: "memory");
                else                asm volatile("s_waitcnt vmcnt(17)" ::: "memory");
                __builtin_amdgcn_s_barrier();
                __builtin_amdgcn_sched_barrier(0);
            }
        }
    }

    // epilogue: out = exp(relu(acc + b1) @ W2 + b2)
    float pv[4][4];
#pragma unroll
    for (int mi = 0; mi < 4; ++mi)
#pragma unroll
        for (int rg = 0; rg < 4; ++rg) pv[mi][rg] = 0.f;

#pragma unroll
    for (int ni = 0; ni < 4; ++ni) {
        int n = wave * 64 + ni * 16 + (lane & 15);
        float b1v = b1[n];
        float w2v = W2[n];
#pragma unroll
        for (int mi = 0; mi < 4; ++mi)
#pragma unroll
            for (int rg = 0; rg < 4; ++rg) {
                float h = fmaxf(acc[mi][ni][rg] + b1v, 0.f);
                pv[mi][rg] = fmaf(h, w2v, pv[mi][rg]);
            }
    }

#pragma unroll
    for (int m = 1; m < 16; m <<= 1)
#pragma unroll
        for (int mi = 0; mi < 4; ++mi)
#pragma unroll
            for (int rg = 0; rg < 4; ++rg)
                pv[mi][rg] += __shfl_xor(pv[mi][rg], m, 64);

    if ((lane & 15) == 0) {
        int rq = lane >> 4;
#pragma unroll
        for (int mi = 0; mi < 4; ++mi)
#pragma unroll
            for (int rg = 0; rg < 4; ++rg)
                atomicAdd(&hsum[mi * 16 + rq * 4 + rg], pv[mi][rg]);
    }
    __syncthreads();

    if (tid < MT) out[m0 + tid] = expf(hsum[tid] + b2[0]);
}

extern "C" void kernel_launch(void* const* d_in, const int* in_sizes, int n_in,
                              void* d_out, int out_size, void* d_ws, size_t ws_size,
                              hipStream_t stream) {
    const float* x    = (const float*)d_in[0];
    const float* emb  = (const float*)d_in[1];
    const float* ctsW = (const float*)d_in[2];
    const float* ctsB = (const float*)d_in[3];
    const float* W1   = (const float*)d_in[4];
    const float* b1   = (const float*)d_in[5];
    const float* W2   = (const float*)d_in[6];
    const float* b2   = (const float*)d_in[7];
    float* out = (float*)d_out;

    const int Bn   = in_sizes[0] / NSEG;                 // 16384
    const int nblk = Bn / MT;                            // 256
    const size_t w1b_bytes = (size_t)HID * KTOT * 2;     // 2,555,904
    const size_t a_bytes   = (size_t)Bn * NSEG * 128;    // 81,788,928
    const int total4 = Bn * NSEG * 4;

    if (ws_size >= w1b_bytes + a_bytes) {
        ushort* W1b = (ushort*)d_ws;
        ushort* Abuf = (ushort*)((char*)d_ws + w1b_bytes);
        int n4 = HID * KTOT / 4;
        w1_to_bf16<<<(n4 + 255) / 256, 256, 0, stream>>>(W1, W1b, n4);
        build_A<<<2048, 256, 0, stream>>>(x, emb, ctsW, ctsB, Abuf, total4);
        gemm_net<true><<<nblk, 512, 0, stream>>>(Abuf, (const void*)W1b, b1, W2, b2, out);
    } else {
        // fallback: A only in ws, W1 read as f32 directly
        ushort* Abuf = (ushort*)d_ws;
        build_A<<<2048, 256, 0, stream>>>(x, emb, ctsW, ctsB, Abuf, total4);
        gemm_net<false><<<nblk, 512, 0, stream>>>(Abuf, (const void*)W1, b1, W2, b2, out);
    }
}

// Round 7
// 109.537 us; speedup vs baseline: 1.6524x; 1.5131x over previous
//
#include <hip/hip_runtime.h>
#include <hip/hip_bf16.h>

typedef __bf16 bf16x8 __attribute__((ext_vector_type(8)));
typedef float  f32x4  __attribute__((ext_vector_type(4)));

#define NSEG   39
#define NCAT   26
#define NCTS   13
#define VOCAB  100000
#define DIM    64
#define HID    512
#define KTOT   2496   // 39*64
#define MT     64     // rows per block
#define NT     256    // cols per block (N-half)

__global__ void w1_to_bf16(const float* __restrict__ w1, ushort* __restrict__ w1b, int n4) {
    int i = blockIdx.x * blockDim.x + threadIdx.x;
    if (i >= n4) return;
    f32x4 v = ((const f32x4*)w1)[i];
    ushort4 o;
    o.x = __builtin_bit_cast(unsigned short, (__bf16)v[0]);
    o.y = __builtin_bit_cast(unsigned short, (__bf16)v[1]);
    o.z = __builtin_bit_cast(unsigned short, (__bf16)v[2]);
    o.w = __builtin_bit_cast(unsigned short, (__bf16)v[3]);
    ((ushort4*)w1b)[i] = o;
}

__global__ void zero_out_k(float* __restrict__ out) {
    out[blockIdx.x * 256 + threadIdx.x] = 0.f;
}

__global__ void exp_out_k(float* __restrict__ out, const float* __restrict__ b2) {
    int i = blockIdx.x * 256 + threadIdx.x;
    out[i] = expf(out[i] + b2[0]);
}

template<bool W1BF>
__global__ __launch_bounds__(512, 4)
void fused_net(const float* __restrict__ x,      // B x 39
               const float* __restrict__ emb,    // 26 x V x 64
               const float* __restrict__ ctsW,   // 13 x 64
               const float* __restrict__ ctsB,   // 13 x 64
               const void*  __restrict__ W1p,    // 512 x 2496 (bf16 or f32)
               const float* __restrict__ b1,     // 512
               const float* __restrict__ W2,     // 512
               float* __restrict__ out)          // B (partial accumulate)
{
    const int tid  = threadIdx.x;
    const int lane = tid & 63;
    const int ng   = tid >> 6;   // wave = 32-col group within this block's N-half

    // pair (bid, bid+8): same mtile, nhalf 0/1, same XCD (bid%8) -> gather L2 reuse
    const int bid   = blockIdx.x;
    const int mtile = (bid >> 4) * 8 + (bid & 7);
    const int nhalf = (bid >> 3) & 1;
    const int m0    = mtile * MT;
    const int n0    = nhalf * NT;

    __shared__ float xs[MT * NSEG];                      // 9984 B
    __shared__ float ctsw_s[NCTS * DIM];                 // 3328 B
    __shared__ float ctsb_s[NCTS * DIM];                 // 3328 B
    __shared__ __align__(16) ushort Abuf[2][MT * DIM];   // 2 x 8 KB bf16, swizzled
    __shared__ float hsum[MT];                           // 256 B

    for (int e = tid; e < MT * NSEG; e += 512)
        xs[e] = x[(size_t)m0 * NSEG + e];
    for (int e = tid; e < NCTS * DIM; e += 512) {
        ctsw_s[e] = ctsW[e];
        ctsb_s[e] = ctsB[e];
    }
    if (tid < MT) hsum[tid] = 0.f;
    __syncthreads();

    // staging: thread -> (row r, 16B slot s); content chunk c = s ^ (r&7)
    const int r = tid >> 3;
    const int s = tid & 7;
    const int c = s ^ (r & 7);

    unsigned bbase[2];
#pragma unroll
    for (int ni = 0; ni < 2; ++ni)
        bbase[ni] = (unsigned)(n0 + ng * 32 + ni * 16 + (lane & 15)) * KTOT + ((lane >> 4) << 3);

    const ushort* W1b = (const ushort*)W1p;
    const float*  W1f = (const float*)W1p;

    // gather ring, depth 3, 32B (8 floats) per thread
    f32x4 g0[3], g1[3];

    auto issueG = [&](int t, int slot) {
        int idx = (int)xs[r * NSEG + t];
        const float* p = emb + ((size_t)t * VOCAB + (size_t)idx) * DIM + c * 8;
        g0[slot] = *(const f32x4*)p;
        g1[slot] = *(const f32x4*)(p + 4);
    };

    auto writeA = [&](int t, int slot, int buf, bool norelu) {
        float vv[8];
        if (t < NCAT) {
#pragma unroll
            for (int k = 0; k < 4; ++k) { vv[k] = g0[slot][k]; vv[4 + k] = g1[slot][k]; }
            if (!norelu) {
#pragma unroll
                for (int k = 0; k < 8; ++k) vv[k] = fmaxf(vv[k], 0.f);
            }
        } else {
            int jj = t - NCAT;
            float sx = xs[r * NSEG + t];
            f32x4 w0 = *(const f32x4*)&ctsw_s[jj * DIM + c * 8];
            f32x4 w1 = *(const f32x4*)&ctsw_s[jj * DIM + c * 8 + 4];
            f32x4 q0 = *(const f32x4*)&ctsb_s[jj * DIM + c * 8];
            f32x4 q1 = *(const f32x4*)&ctsb_s[jj * DIM + c * 8 + 4];
#pragma unroll
            for (int k = 0; k < 4; ++k) {
                vv[k]     = fmaxf(fmaf(sx, w0[k], q0[k]), 0.f);
                vv[4 + k] = fmaxf(fmaf(sx, w1[k], q1[k]), 0.f);
            }
        }
        bf16x8 o;
#pragma unroll
        for (int k = 0; k < 8; ++k) o[k] = (__bf16)vv[k];
        *(bf16x8*)&Abuf[buf][r * DIM + s * 8] = o;
    };

    bf16x8 bfr[2][2][2];  // [set][ks][ni]
    auto loadB = [&](int t, int set) {
#pragma unroll
        for (int ks = 0; ks < 2; ++ks)
#pragma unroll
            for (int ni = 0; ni < 2; ++ni) {
                unsigned off = bbase[ni] + t * 64 + ks * 32;
                if constexpr (W1BF) {
                    bfr[set][ks][ni] = *(const bf16x8*)(W1b + off);
                } else {
                    f32x4 u0 = *(const f32x4*)(W1f + off);
                    f32x4 u1 = *(const f32x4*)(W1f + off + 4);
                    bf16x8 tmp;
#pragma unroll
                    for (int k = 0; k < 4; ++k) {
                        tmp[k]     = (__bf16)u0[k];
                        tmp[4 + k] = (__bf16)u1[k];
                    }
                    bfr[set][ks][ni] = tmp;
                }
            }
    };

    f32x4 acc[4][2];
#pragma unroll
    for (int mi = 0; mi < 4; ++mi)
#pragma unroll
        for (int ni = 0; ni < 2; ++ni)
            acc[mi][ni] = (f32x4){0.f, 0.f, 0.f, 0.f};

    // prologue: fill gather ring (0..2), first B set, stage seg 0
    issueG(0, 0);
    issueG(1, 1);
    issueG(2, 2);
    loadB(0, 0);
    writeA(0, 0, 0, /*norelu=*/true);
    asm volatile("s_waitcnt lgkmcnt(0)" ::: "memory");
    __builtin_amdgcn_s_barrier();
    __builtin_amdgcn_sched_barrier(0);

    // main loop: one barrier per K-step; unroll 6 = lcm(ring 3, dbuf 2)
    for (int tt = 0; tt < 42; tt += 6) {
#pragma unroll
        for (int j = 0; j < 6; ++j) {
            const int t = tt + j;
            if (t < NSEG) {
                const int buf = j & 1;
                if (t + 1 < NSEG) loadB(t + 1, (j + 1) & 1);
                if (t + 3 < NCAT) issueG(t + 3, j % 3);

#pragma unroll
                for (int ks = 0; ks < 2; ++ks) {
                    bf16x8 afr[4];
#pragma unroll
                    for (int mi = 0; mi < 4; ++mi) {
                        int R = mi * 16 + (lane & 15);
                        int C = ks * 4 + (lane >> 4);
                        afr[mi] = *(const bf16x8*)&Abuf[buf][R * DIM + ((C ^ (R & 7)) << 3)];
                    }
#pragma unroll
                    for (int ni = 0; ni < 2; ++ni)
#pragma unroll
                        for (int mi = 0; mi < 4; ++mi)
                            acc[mi][ni] = __builtin_amdgcn_mfma_f32_16x16x32_bf16(
                                afr[mi], bfr[buf][ks][ni], acc[mi][ni], 0, 0, 0);
                }

                if (t + 1 < NSEG) writeA(t + 1, (j + 1) % 3, buf ^ 1, false);

                asm volatile("s_waitcnt lgkmcnt(0)" ::: "memory");
                __builtin_amdgcn_s_barrier();
                __builtin_amdgcn_sched_barrier(0);
            }
        }
    }

    // epilogue: pv = sum over this wave's 32 cols of relu(acc+b1)*W2
    float pv[4][4];
#pragma unroll
    for (int mi = 0; mi < 4; ++mi)
#pragma unroll
        for (int rg = 0; rg < 4; ++rg) pv[mi][rg] = 0.f;

#pragma unroll
    for (int ni = 0; ni < 2; ++ni) {
        int n = n0 + ng * 32 + ni * 16 + (lane & 15);
        float b1v = b1[n];
        float w2v = W2[n];
#pragma unroll
        for (int mi = 0; mi < 4; ++mi)
#pragma unroll
            for (int rg = 0; rg < 4; ++rg) {
                float h = fmaxf(acc[mi][ni][rg] + b1v, 0.f);
                pv[mi][rg] = fmaf(h, w2v, pv[mi][rg]);
            }
    }

#pragma unroll
    for (int m = 1; m < 16; m <<= 1)
#pragma unroll
        for (int mi = 0; mi < 4; ++mi)
#pragma unroll
            for (int rg = 0; rg < 4; ++rg)
                pv[mi][rg] += __shfl_xor(pv[mi][rg], m, 64);

    if ((lane & 15) == 0) {
        int rq = lane >> 4;
#pragma unroll
        for (int mi = 0; mi < 4; ++mi)
#pragma unroll
            for (int rg = 0; rg < 4; ++rg)
                atomicAdd(&hsum[mi * 16 + rq * 4 + rg], pv[mi][rg]);
    }
    __syncthreads();

    if (tid < MT) atomicAdd(&out[m0 + tid], hsum[tid]);
}

extern "C" void kernel_launch(void* const* d_in, const int* in_sizes, int n_in,
                              void* d_out, int out_size, void* d_ws, size_t ws_size,
                              hipStream_t stream) {
    const float* x    = (const float*)d_in[0];
    const float* emb  = (const float*)d_in[1];
    const float* ctsW = (const float*)d_in[2];
    const float* ctsB = (const float*)d_in[3];
    const float* W1   = (const float*)d_in[4];
    const float* b1   = (const float*)d_in[5];
    const float* W2   = (const float*)d_in[6];
    const float* b2   = (const float*)d_in[7];
    float* out = (float*)d_out;

    const int Bn   = in_sizes[0] / NSEG;         // 16384
    const int nblk = (Bn / MT) * 2;              // 512
    const size_t w1b_bytes = (size_t)HID * KTOT * sizeof(unsigned short);

    zero_out_k<<<Bn / 256, 256, 0, stream>>>(out);

    if (ws_size >= w1b_bytes) {
        ushort* W1b = (ushort*)d_ws;
        int n4 = HID * KTOT / 4;
        w1_to_bf16<<<(n4 + 255) / 256, 256, 0, stream>>>(W1, W1b, n4);
        fused_net<true><<<nblk, 512, 0, stream>>>(x, emb, ctsW, ctsB, (const void*)W1b,
                                                  b1, W2, out);
    } else {
        fused_net<false><<<nblk, 512, 0, stream>>>(x, emb, ctsW, ctsB, (const void*)W1,
                                                   b1, W2, out);
    }

    exp_out_k<<<Bn / 256, 256, 0, stream>>>(out, b2);
}

// Round 8
// 102.494 us; speedup vs baseline: 1.7660x; 1.0687x over previous
//
#include <hip/hip_runtime.h>
#include <hip/hip_bf16.h>

typedef __bf16 bf16x8 __attribute__((ext_vector_type(8)));
typedef float  f32x4  __attribute__((ext_vector_type(4)));

#define NSEG   39
#define NCAT   26
#define NCTS   13
#define VOCAB  100000
#define DIM    64
#define HID    512
#define KTOT   2496   // 39*64
#define MT     64     // rows per block

__global__ void w1_to_bf16(const float* __restrict__ w1, ushort* __restrict__ w1b, int n4) {
    int i = blockIdx.x * blockDim.x + threadIdx.x;
    if (i >= n4) return;
    f32x4 v = ((const f32x4*)w1)[i];
    ushort4 o;
    o.x = __builtin_bit_cast(unsigned short, (__bf16)v[0]);
    o.y = __builtin_bit_cast(unsigned short, (__bf16)v[1]);
    o.z = __builtin_bit_cast(unsigned short, (__bf16)v[2]);
    o.w = __builtin_bit_cast(unsigned short, (__bf16)v[3]);
    ((ushort4*)w1b)[i] = o;
}

template<bool W1BF>
__global__ __launch_bounds__(512, 1)
void fused_net(const float* __restrict__ x,      // B x 39
               const float* __restrict__ emb,    // 26 x V x 64
               const float* __restrict__ ctsW,   // 13 x 64
               const float* __restrict__ ctsB,   // 13 x 64
               const void*  __restrict__ W1p,    // 512 x 2496 (bf16 or f32)
               const float* __restrict__ b1,     // 512
               const float* __restrict__ W2,     // 512
               const float* __restrict__ b2,     // 1
               float* __restrict__ out)          // B
{
    const int tid  = threadIdx.x;
    const int lane = tid & 63;
    const int wave = tid >> 6;
    const int m0   = blockIdx.x * MT;

    __shared__ float xs[MT * NSEG];                          // 9984 B
    __shared__ float ctsw_s[NCTS * DIM];                     // 3328 B
    __shared__ float ctsb_s[NCTS * DIM];                     // 3328 B
    __shared__ __align__(16) ushort Abuf[2][2 * MT * DIM];   // 2 bufs x 2 segs x 8KB
    __shared__ float hsum[MT];                               // 256 B

    for (int e = tid; e < MT * NSEG; e += 512)
        xs[e] = x[(size_t)m0 * NSEG + e];
    for (int e = tid; e < NCTS * DIM; e += 512) {
        ctsw_s[e] = ctsW[e];
        ctsb_s[e] = ctsB[e];
    }
    if (tid < MT) hsum[tid] = 0.f;
    __syncthreads();

    // staging: thread -> (row r, 16B slot s); content chunk c = s ^ (r&7)
    const int r = tid >> 3;
    const int s = tid & 7;
    const int c = s ^ (r & 7);

    unsigned bbase[4];
#pragma unroll
    for (int ni = 0; ni < 4; ++ni)
        bbase[ni] = (unsigned)(wave * 64 + ni * 16 + (lane & 15)) * KTOT + ((lane >> 4) << 3);

    const ushort* W1b = (const ushort*)W1p;
    const float*  W1f = (const float*)W1p;

    // gather ring, depth 4 (slot = seg & 3), 32 B per thread per segment
    f32x4 g0[4], g1[4];

    auto issueG = [&](int t, int slot) {
        int idx = (int)xs[r * NSEG + t];
        const float* p = emb + ((size_t)t * VOCAB + (size_t)idx) * DIM + c * 8;
        g0[slot] = *(const f32x4*)p;
        g1[slot] = *(const f32x4*)(p + 4);
    };

    auto writeA = [&](int t, int slot, int buf, bool norelu) {
        float vv[8];
        if (t < NCAT) {
#pragma unroll
            for (int k = 0; k < 4; ++k) { vv[k] = g0[slot][k]; vv[4 + k] = g1[slot][k]; }
            if (!norelu) {
#pragma unroll
                for (int k = 0; k < 8; ++k) vv[k] = fmaxf(vv[k], 0.f);
            }
        } else {
            int jj = t - NCAT;
            float sx = xs[r * NSEG + t];
            f32x4 w0 = *(const f32x4*)&ctsw_s[jj * DIM + c * 8];
            f32x4 w1 = *(const f32x4*)&ctsw_s[jj * DIM + c * 8 + 4];
            f32x4 q0 = *(const f32x4*)&ctsb_s[jj * DIM + c * 8];
            f32x4 q1 = *(const f32x4*)&ctsb_s[jj * DIM + c * 8 + 4];
#pragma unroll
            for (int k = 0; k < 4; ++k) {
                vv[k]     = fmaxf(fmaf(sx, w0[k], q0[k]), 0.f);
                vv[4 + k] = fmaxf(fmaf(sx, w1[k], q1[k]), 0.f);
            }
        }
        bf16x8 o;
#pragma unroll
        for (int k = 0; k < 8; ++k) o[k] = (__bf16)vv[k];
        *(bf16x8*)&Abuf[buf][(t & 1) * (MT * DIM) + r * DIM + s * 8] = o;
    };

    bf16x8 bfr[2][2][4];  // [set: even/odd seg][ks][ni]
    auto loadB = [&](int t, int set) {
#pragma unroll
        for (int ks = 0; ks < 2; ++ks)
#pragma unroll
            for (int ni = 0; ni < 4; ++ni) {
                unsigned off = bbase[ni] + t * 64 + ks * 32;
                if constexpr (W1BF) {
                    bfr[set][ks][ni] = *(const bf16x8*)(W1b + off);
                } else {
                    f32x4 u0 = *(const f32x4*)(W1f + off);
                    f32x4 u1 = *(const f32x4*)(W1f + off + 4);
                    bf16x8 tmp;
#pragma unroll
                    for (int k = 0; k < 4; ++k) {
                        tmp[k]     = (__bf16)u0[k];
                        tmp[4 + k] = (__bf16)u1[k];
                    }
                    bfr[set][ks][ni] = tmp;
                }
            }
    };

    f32x4 acc[4][4];
#pragma unroll
    for (int mi = 0; mi < 4; ++mi)
#pragma unroll
        for (int ni = 0; ni < 4; ++ni)
            acc[mi][ni] = (f32x4){0.f, 0.f, 0.f, 0.f};

    auto mmaSeg = [&](int buf, int half, int set) {
#pragma unroll
        for (int ks = 0; ks < 2; ++ks) {
            bf16x8 afr[4];
#pragma unroll
            for (int mi = 0; mi < 4; ++mi) {
                int R = mi * 16 + (lane & 15);
                int C = ks * 4 + (lane >> 4);
                afr[mi] = *(const bf16x8*)&Abuf[buf][half * (MT * DIM) + R * DIM
                                                    + ((C ^ (R & 7)) << 3)];
            }
#pragma unroll
            for (int ni = 0; ni < 4; ++ni)
#pragma unroll
                for (int mi = 0; mi < 4; ++mi)
                    acc[mi][ni] = __builtin_amdgcn_mfma_f32_16x16x32_bf16(
                        afr[mi], bfr[set][ks][ni], acc[mi][ni], 0, 0, 0);
        }
    };

    // ---------------- prologue: ring segs 0-3, stage segs 0,1 into buf0 ----------------
    issueG(0, 0); issueG(1, 1); issueG(2, 2); issueG(3, 3);
    writeA(0, 0, 0, /*norelu=*/true);
    writeA(1, 1, 0, false);
    asm volatile("s_waitcnt lgkmcnt(0)" ::: "memory");
    __builtin_amdgcn_s_barrier();
    __builtin_amdgcn_sched_barrier(0);

    // ---------------- main loop: 20 phases, 2 K-segments per barrier ----------------
    for (int tt = 0; tt < 40; tt += 8) {
#pragma unroll
        for (int q = 0; q < 4; ++q) {
            const int t0  = tt + 2 * q;
            const int t1  = t0 + 1;
            const int buf = q & 1;

            loadB(t0, 0);
            if (t1 < NSEG) loadB(t1, 1);
            if (t0 + 4 < NCAT) issueG(t0 + 4, (t0 + 4) & 3);
            if (t0 + 5 < NCAT) issueG(t0 + 5, (t0 + 5) & 3);

            mmaSeg(buf, 0, 0);
            if (t1 < NSEG) mmaSeg(buf, 1, 1);

            if (t0 + 2 < NSEG) writeA(t0 + 2, (t0 + 2) & 3, buf ^ 1, false);
            if (t0 + 3 < NSEG) writeA(t0 + 3, (t0 + 3) & 3, buf ^ 1, false);

            asm volatile("s_waitcnt lgkmcnt(0)" ::: "memory");
            __builtin_amdgcn_s_barrier();
            __builtin_amdgcn_sched_barrier(0);
        }
    }

    // ---------------- epilogue: out = exp(relu(acc + b1) @ W2 + b2) ----------------
    float pv[4][4];
#pragma unroll
    for (int mi = 0; mi < 4; ++mi)
#pragma unroll
        for (int rg = 0; rg < 4; ++rg) pv[mi][rg] = 0.f;

#pragma unroll
    for (int ni = 0; ni < 4; ++ni) {
        int n = wave * 64 + ni * 16 + (lane & 15);
        float b1v = b1[n];
        float w2v = W2[n];
#pragma unroll
        for (int mi = 0; mi < 4; ++mi)
#pragma unroll
            for (int rg = 0; rg < 4; ++rg) {
                float h = fmaxf(acc[mi][ni][rg] + b1v, 0.f);
                pv[mi][rg] = fmaf(h, w2v, pv[mi][rg]);
            }
    }

#pragma unroll
    for (int m = 1; m < 16; m <<= 1)
#pragma unroll
        for (int mi = 0; mi < 4; ++mi)
#pragma unroll
            for (int rg = 0; rg < 4; ++rg)
                pv[mi][rg] += __shfl_xor(pv[mi][rg], m, 64);

    if ((lane & 15) == 0) {
        int rq = lane >> 4;
#pragma unroll
        for (int mi = 0; mi < 4; ++mi)
#pragma unroll
            for (int rg = 0; rg < 4; ++rg)
                atomicAdd(&hsum[mi * 16 + rq * 4 + rg], pv[mi][rg]);
    }
    __syncthreads();

    if (tid < MT) out[m0 + tid] = expf(hsum[tid] + b2[0]);
}

extern "C" void kernel_launch(void* const* d_in, const int* in_sizes, int n_in,
                              void* d_out, int out_size, void* d_ws, size_t ws_size,
                              hipStream_t stream) {
    const float* x    = (const float*)d_in[0];
    const float* emb  = (const float*)d_in[1];
    const float* ctsW = (const float*)d_in[2];
    const float* ctsB = (const float*)d_in[3];
    const float* W1   = (const float*)d_in[4];
    const float* b1   = (const float*)d_in[5];
    const float* W2   = (const float*)d_in[6];
    const float* b2   = (const float*)d_in[7];
    float* out = (float*)d_out;

    const int Bn   = in_sizes[0] / NSEG;         // 16384
    const int nblk = Bn / MT;                    // 256
    const size_t w1b_bytes = (size_t)HID * KTOT * sizeof(unsigned short);

    if (ws_size >= w1b_bytes) {
        ushort* W1b = (ushort*)d_ws;
        int n4 = HID * KTOT / 4;
        w1_to_bf16<<<(n4 + 255) / 256, 256, 0, stream>>>(W1, W1b, n4);
        fused_net<true><<<nblk, 512, 0, stream>>>(x, emb, ctsW, ctsB, (const void*)W1b,
                                                  b1, W2, b2, out);
    } else {
        fused_net<false><<<nblk, 512, 0, stream>>>(x, emb, ctsW, ctsB, (const void*)W1,
                                                   b1, W2, b2, out);
    }
}